// Round 7
// baseline (225.567 us; speedup 1.0000x reference)
//
#include <hip/hip_runtime.h>
#include <hip/hip_bf16.h>

typedef __bf16 bf16;
typedef __bf16 bf16x8 __attribute__((ext_vector_type(8)));
typedef __bf16 bf16x4 __attribute__((ext_vector_type(4)));
typedef float  f32x4  __attribute__((ext_vector_type(4)));
typedef float  f32x16 __attribute__((ext_vector_type(16)));

#define B_ 2
#define L_ 2048
#define E_ 1024
#define H_ 16
#define D_ 64

// XOR-swizzled LDS tile: 64 bf16 cols/row as 8 chunks of 8; conflict-free for
// both row-staging writes and column-ish frag reads.
__device__ __forceinline__ int swz(int r, int c) {
    return r * 64 + (((c ^ (r & 7)) & 7) << 3);
}

// async global->LDS DMA, 16B per lane; lds dest = wave-uniform base + lane*16
#define DMA16(gp, lp)                                                              \
    __builtin_amdgcn_global_load_lds(                                              \
        (const __attribute__((address_space(1))) unsigned int*)(gp),               \
        (__attribute__((address_space(3))) unsigned int*)(lp), 16, 0, 0)

// ---------------- fused prep: everything becomes pre-swizzled 8KB tiles ----------------
// [0,1024):    V [b][l][h][d] fp32 -> vt tiles [bh][kt][4096]  (V^T 64d x 64k,
//              k-cols sigma-permuted within each 16-group, swizzled)
// [1024,2048): mask i32 -> mtq2 [b][k>>5][q] u32 (ballot-packed bits along k)
// [2048,3072): K fp32 -> kt tiles [b][h][kt][4096] (64k x 64d, swizzled)
// [3072,3328): W fp32 -> wbt tiles [n6][kt][4096] (64n x 64k, swizzled)
__global__ __launch_bounds__(256) void prep_kernel(const float* __restrict__ v,
                                                   const float* __restrict__ keys,
                                                   const int* __restrict__ mask,
                                                   const float* __restrict__ W,
                                                   bf16* __restrict__ vt_,
                                                   bf16* __restrict__ kt_,
                                                   unsigned int* __restrict__ mtq2,
                                                   bf16* __restrict__ wbt) {
    __shared__ __attribute__((aligned(16))) float tile[64 * 65];
    const int bid = blockIdx.x;
    const int t = threadIdx.x;
    if (bid < 1024) {
        // V transpose + sigma-permute + swizzle
        int bh = bid >> 5, b = bh >> 4, h = bh & 15, kt = bid & 31;
        int kk = t >> 2, dg = t & 3;
        const float* src = v + (((size_t)(b * L_ + kt * 64 + kk)) * H_ + h) * D_ + dg * 16;
        float4 f[4];
#pragma unroll
        for (int i = 0; i < 4; i++) f[i] = reinterpret_cast<const float4*>(src)[i];
#pragma unroll
        for (int i = 0; i < 16; i++)
            tile[(dg * 16 + i) * 65 + kk] = reinterpret_cast<const float*>(f)[i];
        __syncthreads();
        int dd = t >> 2, cg = t & 3;
        const int sig[16] = {0, 1, 2, 3, 8, 9, 10, 11, 4, 5, 6, 7, 12, 13, 14, 15};
        bf16 tmp[16];
#pragma unroll
        for (int p = 0; p < 16; p++)
            tmp[p] = (bf16)tile[dd * 65 + cg * 16 + sig[p]];
        bf16* dst = vt_ + ((size_t)bh * 32 + kt) * 4096;
        *reinterpret_cast<uint4*>(dst + swz(dd, cg * 2))     = *reinterpret_cast<const uint4*>(&tmp[0]);
        *reinterpret_cast<uint4*>(dst + swz(dd, cg * 2 + 1)) = *reinterpret_cast<const uint4*>(&tmp[8]);
    } else if (bid < 2048) {
        int idx = bid - 1024;
        int b = idx >> 9;
        int q = (idx & 511) * 4 + (t >> 6);
        int li = t & 63;
        const int* mrow = mask + ((size_t)b * L_ + q) * L_;
        unsigned int* mq = mtq2 + (size_t)b * 64 * 2048;
#pragma unroll 4
        for (int pass = 0; pass < 32; pass++) {
            int m = mrow[pass * 64 + li];
            unsigned long long bal = __ballot(m & 1);
            if (li == 0) mq[(size_t)(pass * 2) * 2048 + q] = (unsigned int)bal;
            if (li == 1) mq[(size_t)(pass * 2 + 1) * 2048 + q] = (unsigned int)(bal >> 32);
        }
    } else if (bid < 3072) {
        int idx = bid - 2048;
        int b = idx >> 9, h = (idx >> 5) & 15, kt = idx & 31;
        int r = t >> 2, cg = t & 3;
        const float* src = keys + ((size_t)(b * L_ + kt * 64 + r)) * E_ + h * 64 + cg * 16;
        float4 f[4];
#pragma unroll
        for (int i = 0; i < 4; i++) f[i] = reinterpret_cast<const float4*>(src)[i];
        bf16 tmp[16];
#pragma unroll
        for (int i = 0; i < 16; i++)
            tmp[i] = (bf16)reinterpret_cast<const float*>(f)[i];
        bf16* dst = kt_ + ((size_t)(b * 16 + h) * 32 + kt) * 4096;
        *reinterpret_cast<uint4*>(dst + swz(r, cg * 2))     = *reinterpret_cast<const uint4*>(&tmp[0]);
        *reinterpret_cast<uint4*>(dst + swz(r, cg * 2 + 1)) = *reinterpret_cast<const uint4*>(&tmp[8]);
    } else {
        int idx = bid - 3072;
        int n6 = idx >> 4, kt = idx & 15;
        int r = t >> 2, cg = t & 3;
        const float* src = W + ((size_t)(n6 * 64 + r)) * E_ + kt * 64 + cg * 16;
        float4 f[4];
#pragma unroll
        for (int i = 0; i < 4; i++) f[i] = reinterpret_cast<const float4*>(src)[i];
        bf16 tmp[16];
#pragma unroll
        for (int i = 0; i < 16; i++)
            tmp[i] = (bf16)reinterpret_cast<const float*>(f)[i];
        bf16* dst = wbt + ((size_t)(n6 * 16 + kt)) * 4096;
        *reinterpret_cast<uint4*>(dst + swz(r, cg * 2))     = *reinterpret_cast<const uint4*>(&tmp[0]);
        *reinterpret_cast<uint4*>(dst + swz(r, cg * 2 + 1)) = *reinterpret_cast<const uint4*>(&tmp[8]);
    }
}

// ---------------- flash attention: DMA-staged, swap-free P, 32KB LDS ----------------
// Tq=64/block, Tk=64. 4 waves 2x2 (wq x wk): wave = 32q x 32k per ktile.
// S^T = K.Q^T (32x32x16). V's k-cols are sigma-permuted in prep so the S^T
// C-frag packs DIRECTLY into the PV B-operand (no cross-lane ops).
// Row-sum l via an all-ones-A MFMA (every acc element = full K-sum).
// LDS: [K0 0-8K][K1/Qs 8-16K][V0 16-24K][V1 24-32K]; Qs overlays K1 (bq frags
// are extracted before the kt=0 barrier; first DMA into K1 is issued after it).
__global__ __launch_bounds__(256, 5) void attn_kernel(const float* __restrict__ q_,
                                                      const bf16* __restrict__ kt_,
                                                      const bf16* __restrict__ vt_,
                                                      const unsigned int* __restrict__ mtq2,
                                                      bf16* __restrict__ xbt) {
    __shared__ __attribute__((aligned(16))) char smem[32768];
    bf16* Qs = (bf16*)(smem + 8192);
    float* Om = (float*)smem;            // epilogue overlay [64d][64q] (16KB)
    float* Lrow = (float*)(smem + 16384);
    bf16* Xs = (bf16*)(smem + 16640);    // [64][72] bf16 (9216B)

    const int bh = blockIdx.y, b = bh >> 4, hd = bh & 15;
    const int q0 = blockIdx.x * 64;
    const int t = threadIdx.x;
    const int w = t >> 6, lane = t & 63, h = lane >> 5, l31 = lane & 31;
    const int wq = w & 1, wk = w >> 1;
    const int r_ = t >> 2, cg = t & 3;

    const float CSCALE = 1.4426950408889634f / 32.0f;  // log2(e)/sqrt(E)

    const bf16* kbase = kt_ + (size_t)bh * 32 * 4096;
    const bf16* vbase = vt_ + (size_t)bh * 32 * 4096;

    // DMA kt=0 into K0/V0 (2KB per wave per tensor)
    {
        const bf16* gk = kbase + w * 1024 + lane * 8;
        DMA16(gk, smem + w * 2048);
        DMA16(gk + 512, smem + w * 2048 + 1024);
        const bf16* gv = vbase + w * 1024 + lane * 8;
        DMA16(gv, smem + 16384 + w * 2048);
        DMA16(gv + 512, smem + 16384 + w * 2048 + 1024);
    }
    // stage Q (fp32 -> scaled bf16, swizzled) into the K1 region
    {
        const float* src = q_ + ((size_t)(b * L_ + q0 + r_)) * E_ + hd * 64 + cg * 16;
        float4 f[4];
#pragma unroll
        for (int i = 0; i < 4; i++) f[i] = reinterpret_cast<const float4*>(src)[i];
        bf16 tmp[16];
#pragma unroll
        for (int i = 0; i < 16; i++)
            tmp[i] = (bf16)(reinterpret_cast<const float*>(f)[i] * CSCALE);
        *reinterpret_cast<uint4*>(&Qs[swz(r_, cg * 2)])     = *reinterpret_cast<const uint4*>(&tmp[0]);
        *reinterpret_cast<uint4*>(&Qs[swz(r_, cg * 2 + 1)]) = *reinterpret_cast<const uint4*>(&tmp[8]);
    }
    __syncthreads();

    // block-stationary Q^T B-frags: n=q=l31, k-slots = d chunks dc*2+h
    bf16x8 bq[4];
#pragma unroll
    for (int dc = 0; dc < 4; dc++)
        bq[dc] = *reinterpret_cast<const bf16x8*>(&Qs[swz(wq * 32 + l31, dc * 2 + h)]);

    f32x16 oc[2] = {{}, {}};
    f32x16 lacc = {};
    bf16x8 aones;
#pragma unroll
    for (int i = 0; i < 8; i++) aones[i] = (bf16)1.0f;

    const unsigned int* mbase = mtq2 + (size_t)b * 64 * 2048 + q0 + wq * 32 + l31;

    for (int kt = 0; kt < L_ / 64; kt++) {
        __syncthreads();  // implicit vmcnt(0): DMA for kt complete; prior reads of next buffer done
        bf16* Kc = (bf16*)(smem + (kt & 1) * 8192);
        bf16* Vc = (bf16*)(smem + 16384 + (kt & 1) * 8192);
        if (kt + 1 < L_ / 64) {
            char* Kn = smem + ((kt + 1) & 1) * 8192;
            char* Vn = smem + 16384 + ((kt + 1) & 1) * 8192;
            const bf16* gk = kbase + (size_t)(kt + 1) * 4096 + w * 1024 + lane * 8;
            DMA16(gk, Kn + w * 2048);
            DMA16(gk + 512, Kn + w * 2048 + 1024);
            const bf16* gv = vbase + (size_t)(kt + 1) * 4096 + w * 1024 + lane * 8;
            DMA16(gv, Vn + w * 2048);
            DMA16(gv + 512, Vn + w * 2048 + 1024);
        }
        unsigned int mw = mbase[(size_t)(kt * 2 + wk) * 2048];

        // S^T = K.Q^T : 32k x 32q per wave
        f32x16 st = {};
#pragma unroll
        for (int dc = 0; dc < 4; dc++) {
            bf16x8 ak = *reinterpret_cast<const bf16x8*>(&Kc[swz(wk * 32 + l31, dc * 2 + h)]);
            st = __builtin_amdgcn_mfma_f32_32x32x16_bf16(ak, bq[dc], st, 0, 0, 0);
        }

        // P = exp2(S^T)*maskbit, packed straight into B-operand (V is sigma-permuted)
        const unsigned int mwh = mw >> (h * 4);
        bf16x8 bp[2];
        float pv[16];
#pragma unroll
        for (int i = 0; i < 16; i++) {
            const int base = (i & 3) + 8 * (i >> 2);
            float e = __builtin_amdgcn_exp2f(st[i]);
            pv[i] = ((mwh >> base) & 1u) ? e : 0.0f;
        }
#pragma unroll
        for (int kc = 0; kc < 2; kc++)
#pragma unroll
            for (int j = 0; j < 8; j++)
                bp[kc][j] = (bf16)pv[kc * 8 + j];

        // O^T += V^T.P^T ; l^T += ones.P^T (row-sum in the matrix pipe)
#pragma unroll
        for (int da = 0; da < 2; da++)
#pragma unroll
            for (int kc = 0; kc < 2; kc++) {
                bf16x8 av = *reinterpret_cast<const bf16x8*>(&Vc[swz(da * 32 + l31, wk * 4 + kc * 2 + h)]);
                oc[da] = __builtin_amdgcn_mfma_f32_32x32x16_bf16(av, bp[kc], oc[da], 0, 0, 0);
            }
#pragma unroll
        for (int kc = 0; kc < 2; kc++)
            lacc = __builtin_amdgcn_mfma_f32_32x32x16_bf16(aones, bp[kc], lacc, 0, 0, 0);
    }
    __syncthreads();  // all reads of K/V buffers done before epilogue overlays

    // merge wk partials (exact sum), divide, write swizzled x tile
    float lw = lacc[0];  // every acc element = full k-sum for this lane's q
    if (wk == 1) {
#pragma unroll
        for (int da = 0; da < 2; da++)
#pragma unroll
            for (int i = 0; i < 16; i++) {
                int d = da * 32 + (i & 3) + 8 * (i >> 2) + 4 * h;
                Om[d * 64 + wq * 32 + l31] = oc[da][i];
            }
        if (h == 0) Lrow[wq * 32 + l31] = lw;
    }
    __syncthreads();
    if (wk == 0) {
        float rinv = 1.0f / (lw + Lrow[wq * 32 + l31]);
#pragma unroll
        for (int da = 0; da < 2; da++)
#pragma unroll
            for (int g = 0; g < 4; g++) {
                int d0 = da * 32 + 8 * g + 4 * h;
                bf16x4 pk;
#pragma unroll
                for (int r = 0; r < 4; r++)
                    pk[r] = (bf16)((oc[da][g * 4 + r] + Om[(d0 + r) * 64 + wq * 32 + l31]) * rinv);
                *reinterpret_cast<bf16x4*>(&Xs[(wq * 32 + l31) * 72 + d0]) = pk;
            }
    }
    __syncthreads();
    {
        bf16* xtile = xbt + ((size_t)((b * 32 + (q0 >> 6)) * 16 + hd)) * 4096;
        *reinterpret_cast<uint4*>(xtile + swz(r_, cg * 2))     = *reinterpret_cast<const uint4*>(&Xs[r_ * 72 + cg * 16]);
        *reinterpret_cast<uint4*>(xtile + swz(r_, cg * 2 + 1)) = *reinterpret_cast<const uint4*>(&Xs[r_ * 72 + cg * 16 + 8]);
    }
}

// ---------------- projection: out = x W^T + b ; 128x64 tiles, DMA double-buffer ----------------
__global__ __launch_bounds__(256, 3) void proj_kernel(const bf16* __restrict__ xbt,
                                                      const bf16* __restrict__ wbt,
                                                      const float* __restrict__ bias,
                                                      float* __restrict__ out) {
    __shared__ __attribute__((aligned(16))) char smem[49152];
    // As(p) = smem + p*16384 (2 tiles of 8KB) ; Bs(p) = smem + 32768 + p*8192
    const int n0 = blockIdx.x * 64, m0 = blockIdx.y * 128;
    const int t = threadIdx.x;
    const int w = t >> 6, lane = t & 63, h = lane >> 5, l31 = lane & 31;
    const int wm = w >> 1, wn = w & 1;

    const bf16* a0 = xbt + ((size_t)(m0 >> 6)) * 16 * 4096;       // tile row m6
    const bf16* a1 = a0 + 16 * 4096;                              // tile row m6+1
    const bf16* bb_ = wbt + ((size_t)(n0 >> 6)) * 16 * 4096;

    // DMA kt=0
    {
#pragma unroll
        for (int i = 0; i < 4; i++) {
            int c = w * 4 + i;  // 16 x 1KB chunks over A (2 tiles)
            const bf16* g = ((c >> 3) ? a1 : a0) + (c & 7) * 512 + lane * 8;
            DMA16(g, smem + c * 1024);
        }
#pragma unroll
        for (int i = 0; i < 2; i++) {
            int c = w * 2 + i;
            DMA16(bb_ + c * 512 + lane * 8, smem + 32768 + c * 1024);
        }
    }

    f32x16 acc[2] = {{}, {}};
    for (int kt = 0; kt < E_ / 64; kt++) {
        __syncthreads();
        bf16* Ac = (bf16*)(smem + (kt & 1) * 16384);
        bf16* Bc = (bf16*)(smem + 32768 + (kt & 1) * 8192);
        if (kt + 1 < E_ / 64) {
            char* An = smem + ((kt + 1) & 1) * 16384;
            char* Bn = smem + 32768 + ((kt + 1) & 1) * 8192;
            const bf16* an0 = a0 + (kt + 1) * 4096;
            const bf16* an1 = a1 + (kt + 1) * 4096;
            const bf16* bn = bb_ + (kt + 1) * 4096;
#pragma unroll
            for (int i = 0; i < 4; i++) {
                int c = w * 4 + i;
                const bf16* g = ((c >> 3) ? an1 : an0) + (c & 7) * 512 + lane * 8;
                DMA16(g, An + c * 1024);
            }
#pragma unroll
            for (int i = 0; i < 2; i++) {
                int c = w * 2 + i;
                DMA16(bn + c * 512 + lane * 8, Bn + c * 1024);
            }
        }
#pragma unroll
        for (int dc = 0; dc < 4; dc++) {
            bf16x8 bfr = *reinterpret_cast<const bf16x8*>(&Bc[swz(wn * 32 + l31, dc * 2 + h)]);
#pragma unroll
            for (int mi = 0; mi < 2; mi++) {
                bf16x8 afr = *reinterpret_cast<const bf16x8*>(&Ac[wm * 4096 + swz(mi * 32 + l31, dc * 2 + h)]);
                acc[mi] = __builtin_amdgcn_mfma_f32_32x32x16_bf16(afr, bfr, acc[mi], 0, 0, 0);
            }
        }
    }

    float bv = bias[n0 + wn * 32 + l31];
#pragma unroll
    for (int mi = 0; mi < 2; mi++)
#pragma unroll
        for (int i = 0; i < 16; i++) {
            int row = m0 + wm * 64 + mi * 32 + (i & 3) + 8 * (i >> 2) + 4 * h;
            out[(size_t)row * E_ + n0 + wn * 32 + l31] = acc[mi][i] + bv;
        }
}

extern "C" void kernel_launch(void* const* d_in, const int* in_sizes, int n_in,
                              void* d_out, int out_size, void* d_ws, size_t ws_size,
                              hipStream_t stream) {
    (void)in_sizes; (void)n_in; (void)out_size; (void)ws_size;
    const float* values = (const float*)d_in[0];
    const float* keys   = (const float*)d_in[1];
    const float* query  = (const float*)d_in[2];
    const int*   mask   = (const int*)d_in[3];
    const float* W_out  = (const float*)d_in[4];
    const float* b_out  = (const float*)d_in[5];
    float* out = (float*)d_out;

    char* ws = (char*)d_ws;
    bf16* vt_ = (bf16*)(ws);                               // 8 MB  V^T tiles [bh][kt][4096] (sigma-permuted, swizzled)
    bf16* kt_ = (bf16*)(ws + 8388608);                     // 8 MB  K tiles [b][h][kt][4096] (swizzled)
    bf16* wbt = (bf16*)(ws + 16777216);                    // 2 MB  W tiles [n6][kt][4096] (swizzled)
    unsigned int* mtq2 = (unsigned int*)(ws + 18874368);   // 1 MB  [b][k>>5][q] u32
    bf16* xbt = (bf16*)(ws + 19922944);                    // 8 MB  x tiles [m6][hd][4096] (swizzled)

    prep_kernel<<<3328, 256, 0, stream>>>(values, keys, mask, W_out, vt_, kt_, mtq2, wbt);
    attn_kernel<<<dim3(L_ / 64, B_ * H_), 256, 0, stream>>>(query, kt_, vt_, mtq2, xbt);
    proj_kernel<<<dim3(E_ / 64, (B_ * L_) / 128), 256, 0, stream>>>(xbt, wbt, b_out, out);
}

// Round 8
// 211.513 us; speedup vs baseline: 1.0664x; 1.0664x over previous
//
#include <hip/hip_runtime.h>
#include <hip/hip_bf16.h>

typedef __bf16 bf16;
typedef __bf16 bf16x8 __attribute__((ext_vector_type(8)));
typedef __bf16 bf16x4 __attribute__((ext_vector_type(4)));
typedef float  f32x4  __attribute__((ext_vector_type(4)));
typedef float  f32x16 __attribute__((ext_vector_type(16)));

#define B_ 2
#define L_ 2048
#define E_ 1024
#define H_ 16
#define D_ 64

// XOR-swizzled LDS tile: 64 bf16 cols/row as 8 chunks of 8; conflict-free for
// both row-staging writes and column-ish frag reads.
__device__ __forceinline__ int swz(int r, int c) {
    return r * 64 + (((c ^ (r & 7)) & 7) << 3);
}

// async global->LDS DMA, 16B per lane; lds dest = wave-uniform base + lane*16
#define DMA16(gp, lp)                                                              \
    __builtin_amdgcn_global_load_lds(                                              \
        (const __attribute__((address_space(1))) unsigned int*)(gp),               \
        (__attribute__((address_space(3))) unsigned int*)(lp), 16, 0, 0)

// ---------------- fused prep: everything becomes pre-swizzled 8KB tiles ----------------
// [0,1024):    V [b][l][h][d] fp32 -> vt tiles [bh][kt][4096]  (V^T 64d x 64k,
//              k-cols sigma-permuted within each 16-group, swizzled)
// [1024,2048): mask i32 -> mtq2 [b][k>>5][q] u32 (ballot-packed bits along k)
// [2048,3072): K fp32 -> kt tiles [b][h][kt][4096] (64k x 64d, swizzled)
// [3072,3328): W fp32 -> wbt tiles [n6][kt][4096] (64n x 64k, swizzled)
__global__ __launch_bounds__(256) void prep_kernel(const float* __restrict__ v,
                                                   const float* __restrict__ keys,
                                                   const int* __restrict__ mask,
                                                   const float* __restrict__ W,
                                                   bf16* __restrict__ vt_,
                                                   bf16* __restrict__ kt_,
                                                   unsigned int* __restrict__ mtq2,
                                                   bf16* __restrict__ wbt) {
    __shared__ __attribute__((aligned(16))) float tile[64 * 65];
    const int bid = blockIdx.x;
    const int t = threadIdx.x;
    if (bid < 1024) {
        // V transpose + sigma-permute + swizzle
        int bh = bid >> 5, b = bh >> 4, h = bh & 15, kt = bid & 31;
        int kk = t >> 2, dg = t & 3;
        const float* src = v + (((size_t)(b * L_ + kt * 64 + kk)) * H_ + h) * D_ + dg * 16;
        float4 f[4];
#pragma unroll
        for (int i = 0; i < 4; i++) f[i] = reinterpret_cast<const float4*>(src)[i];
#pragma unroll
        for (int i = 0; i < 16; i++)
            tile[(dg * 16 + i) * 65 + kk] = reinterpret_cast<const float*>(f)[i];
        __syncthreads();
        int dd = t >> 2, cg = t & 3;
        const int sig[16] = {0, 1, 2, 3, 8, 9, 10, 11, 4, 5, 6, 7, 12, 13, 14, 15};
        bf16 tmp[16];
#pragma unroll
        for (int p = 0; p < 16; p++)
            tmp[p] = (bf16)tile[dd * 65 + cg * 16 + sig[p]];
        bf16* dst = vt_ + ((size_t)bh * 32 + kt) * 4096;
        *reinterpret_cast<uint4*>(dst + swz(dd, cg * 2))     = *reinterpret_cast<const uint4*>(&tmp[0]);
        *reinterpret_cast<uint4*>(dst + swz(dd, cg * 2 + 1)) = *reinterpret_cast<const uint4*>(&tmp[8]);
    } else if (bid < 2048) {
        int idx = bid - 1024;
        int b = idx >> 9;
        int q = (idx & 511) * 4 + (t >> 6);
        int li = t & 63;
        const int* mrow = mask + ((size_t)b * L_ + q) * L_;
        unsigned int* mq = mtq2 + (size_t)b * 64 * 2048;
#pragma unroll 4
        for (int pass = 0; pass < 32; pass++) {
            int m = mrow[pass * 64 + li];
            unsigned long long bal = __ballot(m & 1);
            if (li == 0) mq[(size_t)(pass * 2) * 2048 + q] = (unsigned int)bal;
            if (li == 1) mq[(size_t)(pass * 2 + 1) * 2048 + q] = (unsigned int)(bal >> 32);
        }
    } else if (bid < 3072) {
        int idx = bid - 2048;
        int b = idx >> 9, h = (idx >> 5) & 15, kt = idx & 31;
        int r = t >> 2, cg = t & 3;
        const float* src = keys + ((size_t)(b * L_ + kt * 64 + r)) * E_ + h * 64 + cg * 16;
        float4 f[4];
#pragma unroll
        for (int i = 0; i < 4; i++) f[i] = reinterpret_cast<const float4*>(src)[i];
        bf16 tmp[16];
#pragma unroll
        for (int i = 0; i < 16; i++)
            tmp[i] = (bf16)reinterpret_cast<const float*>(f)[i];
        bf16* dst = kt_ + ((size_t)(b * 16 + h) * 32 + kt) * 4096;
        *reinterpret_cast<uint4*>(dst + swz(r, cg * 2))     = *reinterpret_cast<const uint4*>(&tmp[0]);
        *reinterpret_cast<uint4*>(dst + swz(r, cg * 2 + 1)) = *reinterpret_cast<const uint4*>(&tmp[8]);
    } else {
        int idx = bid - 3072;
        int n6 = idx >> 4, kt = idx & 15;
        int r = t >> 2, cg = t & 3;
        const float* src = W + ((size_t)(n6 * 64 + r)) * E_ + kt * 64 + cg * 16;
        float4 f[4];
#pragma unroll
        for (int i = 0; i < 4; i++) f[i] = reinterpret_cast<const float4*>(src)[i];
        bf16 tmp[16];
#pragma unroll
        for (int i = 0; i < 16; i++)
            tmp[i] = (bf16)reinterpret_cast<const float*>(f)[i];
        bf16* dst = wbt + ((size_t)(n6 * 16 + kt)) * 4096;
        *reinterpret_cast<uint4*>(dst + swz(r, cg * 2))     = *reinterpret_cast<const uint4*>(&tmp[0]);
        *reinterpret_cast<uint4*>(dst + swz(r, cg * 2 + 1)) = *reinterpret_cast<const uint4*>(&tmp[8]);
    }
}

// ---------------- flash attention: DMA-staged, swap-free P, 32KB LDS ----------------
// Tq=64/block, Tk=64. 4 waves 2x2 (wq x wk): wave = 32q x 32k per ktile.
// S^T = K.Q^T (32x32x16). V's k-cols are sigma-permuted in prep so the S^T
// C-frag packs DIRECTLY into the PV B-operand (no cross-lane ops).
// Row-sum l via an all-ones-A MFMA (every acc element = full K-sum).
// LDS: [K0 0-8K][K1/Qs 8-16K][V0 16-24K][V1 24-32K]; Qs overlays K1 (bq frags
// are extracted before the kt=0 barrier; first DMA into K1 is issued after it).
// launch_bounds min-waves=4: 5 forced a VGPR cap -> scratch spills
// (WRITE_SIZE 8->33 MB, r7). Occupancy is LDS-limited at 5 blocks/CU anyway.
__global__ __launch_bounds__(256, 4) void attn_kernel(const float* __restrict__ q_,
                                                      const bf16* __restrict__ kt_,
                                                      const bf16* __restrict__ vt_,
                                                      const unsigned int* __restrict__ mtq2,
                                                      bf16* __restrict__ xbt) {
    __shared__ __attribute__((aligned(16))) char smem[32768];
    bf16* Qs = (bf16*)(smem + 8192);
    float* Om = (float*)smem;            // epilogue overlay [64d][64q] (16KB)
    float* Lrow = (float*)(smem + 16384);
    bf16* Xs = (bf16*)(smem + 16640);    // [64][72] bf16 (9216B)

    const int bh = blockIdx.y, b = bh >> 4, hd = bh & 15;
    const int q0 = blockIdx.x * 64;
    const int t = threadIdx.x;
    const int w = t >> 6, lane = t & 63, h = lane >> 5, l31 = lane & 31;
    const int wq = w & 1, wk = w >> 1;
    const int r_ = t >> 2, cg = t & 3;

    const float CSCALE = 1.4426950408889634f / 32.0f;  // log2(e)/sqrt(E)

    const bf16* kbase = kt_ + (size_t)bh * 32 * 4096;
    const bf16* vbase = vt_ + (size_t)bh * 32 * 4096;

    // DMA kt=0 into K0/V0 (2KB per wave per tensor)
    {
        const bf16* gk = kbase + w * 1024 + lane * 8;
        DMA16(gk, smem + w * 2048);
        DMA16(gk + 512, smem + w * 2048 + 1024);
        const bf16* gv = vbase + w * 1024 + lane * 8;
        DMA16(gv, smem + 16384 + w * 2048);
        DMA16(gv + 512, smem + 16384 + w * 2048 + 1024);
    }
    // stage Q (fp32 -> scaled bf16, swizzled) into the K1 region
    {
        const float* src = q_ + ((size_t)(b * L_ + q0 + r_)) * E_ + hd * 64 + cg * 16;
        float4 f[4];
#pragma unroll
        for (int i = 0; i < 4; i++) f[i] = reinterpret_cast<const float4*>(src)[i];
        bf16 tmp[16];
#pragma unroll
        for (int i = 0; i < 16; i++)
            tmp[i] = (bf16)(reinterpret_cast<const float*>(f)[i] * CSCALE);
        *reinterpret_cast<uint4*>(&Qs[swz(r_, cg * 2)])     = *reinterpret_cast<const uint4*>(&tmp[0]);
        *reinterpret_cast<uint4*>(&Qs[swz(r_, cg * 2 + 1)]) = *reinterpret_cast<const uint4*>(&tmp[8]);
    }
    __syncthreads();

    // block-stationary Q^T B-frags: n=q=l31, k-slots = d chunks dc*2+h
    bf16x8 bq[4];
#pragma unroll
    for (int dc = 0; dc < 4; dc++)
        bq[dc] = *reinterpret_cast<const bf16x8*>(&Qs[swz(wq * 32 + l31, dc * 2 + h)]);

    f32x16 oc[2] = {{}, {}};
    f32x16 lacc = {};
    bf16x8 aones;
#pragma unroll
    for (int i = 0; i < 8; i++) aones[i] = (bf16)1.0f;

    const unsigned int* mbase = mtq2 + (size_t)b * 64 * 2048 + q0 + wq * 32 + l31;

    for (int kt = 0; kt < L_ / 64; kt++) {
        __syncthreads();  // implicit vmcnt(0): DMA for kt complete; prior reads of next buffer done
        bf16* Kc = (bf16*)(smem + (kt & 1) * 8192);
        bf16* Vc = (bf16*)(smem + 16384 + (kt & 1) * 8192);
        if (kt + 1 < L_ / 64) {
            char* Kn = smem + ((kt + 1) & 1) * 8192;
            char* Vn = smem + 16384 + ((kt + 1) & 1) * 8192;
            const bf16* gk = kbase + (size_t)(kt + 1) * 4096 + w * 1024 + lane * 8;
            DMA16(gk, Kn + w * 2048);
            DMA16(gk + 512, Kn + w * 2048 + 1024);
            const bf16* gv = vbase + (size_t)(kt + 1) * 4096 + w * 1024 + lane * 8;
            DMA16(gv, Vn + w * 2048);
            DMA16(gv + 512, Vn + w * 2048 + 1024);
        }
        unsigned int mw = mbase[(size_t)(kt * 2 + wk) * 2048];

        // S^T = K.Q^T : 32k x 32q per wave
        f32x16 st = {};
#pragma unroll
        for (int dc = 0; dc < 4; dc++) {
            bf16x8 ak = *reinterpret_cast<const bf16x8*>(&Kc[swz(wk * 32 + l31, dc * 2 + h)]);
            st = __builtin_amdgcn_mfma_f32_32x32x16_bf16(ak, bq[dc], st, 0, 0, 0);
        }

        // P = exp2(S^T)*maskbit, packed straight into B-operand (V is sigma-permuted)
        const unsigned int mwh = mw >> (h * 4);
        bf16x8 bp[2];
        float pv[16];
#pragma unroll
        for (int i = 0; i < 16; i++) {
            const int base = (i & 3) + 8 * (i >> 2);
            float e = __builtin_amdgcn_exp2f(st[i]);
            pv[i] = ((mwh >> base) & 1u) ? e : 0.0f;
        }
#pragma unroll
        for (int kc = 0; kc < 2; kc++)
#pragma unroll
            for (int j = 0; j < 8; j++)
                bp[kc][j] = (bf16)pv[kc * 8 + j];

        // O^T += V^T.P^T ; l^T += ones.P^T (row-sum in the matrix pipe)
#pragma unroll
        for (int da = 0; da < 2; da++)
#pragma unroll
            for (int kc = 0; kc < 2; kc++) {
                bf16x8 av = *reinterpret_cast<const bf16x8*>(&Vc[swz(da * 32 + l31, wk * 4 + kc * 2 + h)]);
                oc[da] = __builtin_amdgcn_mfma_f32_32x32x16_bf16(av, bp[kc], oc[da], 0, 0, 0);
            }
#pragma unroll
        for (int kc = 0; kc < 2; kc++)
            lacc = __builtin_amdgcn_mfma_f32_32x32x16_bf16(aones, bp[kc], lacc, 0, 0, 0);
    }
    __syncthreads();  // all reads of K/V buffers done before epilogue overlays

    // merge wk partials (exact sum), divide, write swizzled x tile
    float lw = lacc[0];  // every acc element = full k-sum for this lane's q
    if (wk == 1) {
#pragma unroll
        for (int da = 0; da < 2; da++)
#pragma unroll
            for (int i = 0; i < 16; i++) {
                int d = da * 32 + (i & 3) + 8 * (i >> 2) + 4 * h;
                Om[d * 64 + wq * 32 + l31] = oc[da][i];
            }
        if (h == 0) Lrow[wq * 32 + l31] = lw;
    }
    __syncthreads();
    if (wk == 0) {
        float rinv = 1.0f / (lw + Lrow[wq * 32 + l31]);
#pragma unroll
        for (int da = 0; da < 2; da++)
#pragma unroll
            for (int g = 0; g < 4; g++) {
                int d0 = da * 32 + 8 * g + 4 * h;
                bf16x4 pk;
#pragma unroll
                for (int r = 0; r < 4; r++)
                    pk[r] = (bf16)((oc[da][g * 4 + r] + Om[(d0 + r) * 64 + wq * 32 + l31]) * rinv);
                *reinterpret_cast<bf16x4*>(&Xs[(wq * 32 + l31) * 72 + d0]) = pk;
            }
    }
    __syncthreads();
    {
        bf16* xtile = xbt + ((size_t)((b * 32 + (q0 >> 6)) * 16 + hd)) * 4096;
        *reinterpret_cast<uint4*>(xtile + swz(r_, cg * 2))     = *reinterpret_cast<const uint4*>(&Xs[r_ * 72 + cg * 16]);
        *reinterpret_cast<uint4*>(xtile + swz(r_, cg * 2 + 1)) = *reinterpret_cast<const uint4*>(&Xs[r_ * 72 + cg * 16 + 8]);
    }
}

// ---------------- projection: out = x W^T + b ; 128x64 tiles, DMA double-buffer ----------------
__global__ __launch_bounds__(256, 3) void proj_kernel(const bf16* __restrict__ xbt,
                                                      const bf16* __restrict__ wbt,
                                                      const float* __restrict__ bias,
                                                      float* __restrict__ out) {
    __shared__ __attribute__((aligned(16))) char smem[49152];
    // As(p) = smem + p*16384 (2 tiles of 8KB) ; Bs(p) = smem + 32768 + p*8192
    const int n0 = blockIdx.x * 64, m0 = blockIdx.y * 128;
    const int t = threadIdx.x;
    const int w = t >> 6, lane = t & 63, h = lane >> 5, l31 = lane & 31;
    const int wm = w >> 1, wn = w & 1;

    const bf16* a0 = xbt + ((size_t)(m0 >> 6)) * 16 * 4096;       // tile row m6
    const bf16* a1 = a0 + 16 * 4096;                              // tile row m6+1
    const bf16* bb_ = wbt + ((size_t)(n0 >> 6)) * 16 * 4096;

    // DMA kt=0
    {
#pragma unroll
        for (int i = 0; i < 4; i++) {
            int c = w * 4 + i;  // 16 x 1KB chunks over A (2 tiles)
            const bf16* g = ((c >> 3) ? a1 : a0) + (c & 7) * 512 + lane * 8;
            DMA16(g, smem + c * 1024);
        }
#pragma unroll
        for (int i = 0; i < 2; i++) {
            int c = w * 2 + i;
            DMA16(bb_ + c * 512 + lane * 8, smem + 32768 + c * 1024);
        }
    }

    f32x16 acc[2] = {{}, {}};
    for (int kt = 0; kt < E_ / 64; kt++) {
        __syncthreads();
        bf16* Ac = (bf16*)(smem + (kt & 1) * 16384);
        bf16* Bc = (bf16*)(smem + 32768 + (kt & 1) * 8192);
        if (kt + 1 < E_ / 64) {
            char* An = smem + ((kt + 1) & 1) * 16384;
            char* Bn = smem + 32768 + ((kt + 1) & 1) * 8192;
            const bf16* an0 = a0 + (kt + 1) * 4096;
            const bf16* an1 = a1 + (kt + 1) * 4096;
            const bf16* bn = bb_ + (kt + 1) * 4096;
#pragma unroll
            for (int i = 0; i < 4; i++) {
                int c = w * 4 + i;
                const bf16* g = ((c >> 3) ? an1 : an0) + (c & 7) * 512 + lane * 8;
                DMA16(g, An + c * 1024);
            }
#pragma unroll
            for (int i = 0; i < 2; i++) {
                int c = w * 2 + i;
                DMA16(bn + c * 512 + lane * 8, Bn + c * 1024);
            }
        }
#pragma unroll
        for (int dc = 0; dc < 4; dc++) {
            bf16x8 bfr = *reinterpret_cast<const bf16x8*>(&Bc[swz(wn * 32 + l31, dc * 2 + h)]);
#pragma unroll
            for (int mi = 0; mi < 2; mi++) {
                bf16x8 afr = *reinterpret_cast<const bf16x8*>(&Ac[wm * 4096 + swz(mi * 32 + l31, dc * 2 + h)]);
                acc[mi] = __builtin_amdgcn_mfma_f32_32x32x16_bf16(afr, bfr, acc[mi], 0, 0, 0);
            }
        }
    }

    float bv = bias[n0 + wn * 32 + l31];
#pragma unroll
    for (int mi = 0; mi < 2; mi++)
#pragma unroll
        for (int i = 0; i < 16; i++) {
            int row = m0 + wm * 64 + mi * 32 + (i & 3) + 8 * (i >> 2) + 4 * h;
            out[(size_t)row * E_ + n0 + wn * 32 + l31] = acc[mi][i] + bv;
        }
}

extern "C" void kernel_launch(void* const* d_in, const int* in_sizes, int n_in,
                              void* d_out, int out_size, void* d_ws, size_t ws_size,
                              hipStream_t stream) {
    (void)in_sizes; (void)n_in; (void)out_size; (void)ws_size;
    const float* values = (const float*)d_in[0];
    const float* keys   = (const float*)d_in[1];
    const float* query  = (const float*)d_in[2];
    const int*   mask   = (const int*)d_in[3];
    const float* W_out  = (const float*)d_in[4];
    const float* b_out  = (const float*)d_in[5];
    float* out = (float*)d_out;

    char* ws = (char*)d_ws;
    bf16* vt_ = (bf16*)(ws);                               // 8 MB  V^T tiles [bh][kt][4096] (sigma-permuted, swizzled)
    bf16* kt_ = (bf16*)(ws + 8388608);                     // 8 MB  K tiles [b][h][kt][4096] (swizzled)
    bf16* wbt = (bf16*)(ws + 16777216);                    // 2 MB  W tiles [n6][kt][4096] (swizzled)
    unsigned int* mtq2 = (unsigned int*)(ws + 18874368);   // 1 MB  [b][k>>5][q] u32
    bf16* xbt = (bf16*)(ws + 19922944);                    // 8 MB  x tiles [m6][hd][4096] (swizzled)

    prep_kernel<<<3328, 256, 0, stream>>>(values, keys, mask, W_out, vt_, kt_, mtq2, wbt);
    attn_kernel<<<dim3(L_ / 64, B_ * H_), 256, 0, stream>>>(query, kt_, vt_, mtq2, xbt);
    proj_kernel<<<dim3(E_ / 64, (B_ * L_) / 128), 256, 0, stream>>>(xbt, wbt, b_out, out);
}